// Round 1
// baseline (1887.467 us; speedup 1.0000x reference)
//
#include <hip/hip_runtime.h>

#define EPS 0.001f

// ---- problem sizes ----
constexpr int Bn = 8, CinN = 4, Tx = 20, Dx = 24, Hx = 24, Wx = 24;
constexpr int Cmid = 12, CoutN = 36;
constexpr int T1 = 18, D1 = 22, H1n = 22, W1n = 22;   // conv1 output dims
constexpr int T2 = 16, D2 = 20, H2n = 20, W2n = 20;   // conv2 output dims

// ---- strides ----
constexpr int SXH = Wx;                 // 24
constexpr int SXD = Hx * Wx;            // 576
constexpr int SXT = Dx * Hx * Wx;       // 13824
constexpr int SXC = Tx * SXT;           // 276480
constexpr long SXB = (long)CinN * SXC;  // 1105920

constexpr int S1H = W1n;                // 22
constexpr int S1D = H1n * W1n;          // 484
constexpr int S1T = D1 * S1D;           // 10648
constexpr int S1C = T1 * S1T;           // 191664
constexpr long S1B = (long)Cmid * S1C;  // 2299968

constexpr int S2H = W2n;                // 20
constexpr int S2D = H2n * W2n;          // 400
constexpr int S2T = D2 * S2D;           // 8000
constexpr int S2O = T2 * S2T;           // 128000
constexpr long S2B = (long)CoutN * S2O; // 4608000

// ---- ws layout (float offsets) ----
// stats[24] @ 0 ; b2ws[36] @ 32 ; W1t[3888] @ 128 ; W2s[34992] @ 4096 ; h1 @ 40960

// Transpose W1 [o][cin][kt][kd][kh][kw] -> W1t [cin*81 + tap][o] (o contiguous)
__global__ void k_w1t(const float* __restrict__ W1, float* __restrict__ W1t) {
    int i = blockIdx.x * 256 + threadIdx.x;
    if (i < Cmid * CinN * 81) {
        int o = i / 324;            // Cin*81 = 324
        int r = i - o * 324;
        W1t[r * Cmid + o] = W1[i];
    }
}

// conv1 + relu + per-channel sum/sumsq
__global__ __launch_bounds__(1024) void k_conv1(
    const float* __restrict__ x, const float* __restrict__ W1t,
    const float* __restrict__ b1, float* __restrict__ h1,
    float* __restrict__ stats)
{
    __shared__ float st[4 * 576];       // 4 d-planes of 24x24
    __shared__ float ssum[Cmid], ssq[Cmid];

    const int tid = threadIdx.x;
    const int dp = blockIdx.x;          // 0..10  -> d0 = 2*dp
    const int t  = blockIdx.y;          // 0..17
    const int b  = blockIdx.z;          // 0..7
    const int d0 = dp * 2;

    const bool active = tid < 968;      // 2*22*22 positions
    int dd = 0, h = 0, w = 0;
    if (active) { dd = tid / 484; int r = tid - dd * 484; h = r / 22; w = r - h * 22; }

    float acc[12];
#pragma unroll
    for (int c = 0; c < 12; ++c) acc[c] = 0.f;

    if (tid < 12) ssum[tid] = 0.f;
    else if (tid < 24) ssq[tid - 12] = 0.f;

    const int lbase = dd * 576 + h * 24 + w;

    for (int cin = 0; cin < 4; ++cin) {
        for (int kt = 0; kt < 3; ++kt) {
            __syncthreads();
            // x[b, cin, t+kt, d0..d0+3, :, :] is contiguous: linear copy
            const float* src = x + (long)b * SXB + (long)cin * SXC
                             + (long)(t + kt) * SXT + (long)d0 * SXD;
            for (int s = tid; s < 2304; s += 1024) st[s] = src[s];
            __syncthreads();
            if (active) {
                const float* wp = W1t + (cin * 81 + kt * 27) * 12;
#pragma unroll
                for (int kd = 0; kd < 3; ++kd)
#pragma unroll
                for (int kh = 0; kh < 3; ++kh)
#pragma unroll
                for (int kw = 0; kw < 3; ++kw) {
                    float xv = st[lbase + kd * 576 + kh * 24 + kw];
                    const float* wq = wp + (kd * 9 + kh * 3 + kw) * 12;
#pragma unroll
                    for (int c = 0; c < 12; ++c) acc[c] = fmaf(wq[c], xv, acc[c]);
                }
            }
        }
    }

    // epilogue: bias + relu + store + per-channel reduction
    const long obase = (long)b * S1B + (long)t * S1T + (long)(d0 + dd) * S1D
                     + (long)h * S1H + w;
    const int lane = tid & 63;
#pragma unroll
    for (int c = 0; c < 12; ++c) {
        float v = 0.f;
        if (active) {
            v = fmaxf(acc[c] + b1[c], 0.f);
            h1[obase + (long)c * S1C] = v;
        }
        float s = v, q = v * v;
#pragma unroll
        for (int off = 32; off > 0; off >>= 1) {
            s += __shfl_down(s, off);
            q += __shfl_down(q, off);
        }
        if (lane == 0) { atomicAdd(&ssum[c], s); atomicAdd(&ssq[c], q); }
    }
    __syncthreads();
    if (tid < 12) atomicAdd(&stats[tid], ssum[tid]);
    else if (tid < 24) atomicAdd(&stats[tid], ssq[tid - 12]);
}

// finalize stats; fold BN affine into W2 (scaled, cout-contiguous) and bias
__global__ void k_fin(const float* __restrict__ stats, const float* __restrict__ gamma,
                      const float* __restrict__ beta, const float* __restrict__ W2,
                      const float* __restrict__ b2, float* __restrict__ W2s,
                      float* __restrict__ b2ws)
{
    __shared__ float a_s[12], d_s[12];
    const int tid = threadIdx.x;
    if (tid < 12) {
        const float N = (float)((long)Bn * T1 * D1 * H1n * W1n); // 1,533,312
        float mean = stats[tid] / N;
        float var  = stats[12 + tid] / N - mean * mean;
        float a = gamma[tid] * (1.0f / sqrtf(var + EPS));
        a_s[tid] = a;
        d_s[tid] = beta[tid] - mean * a;
    }
    if (tid < 36) b2ws[tid] = b2[tid];
    __syncthreads();
    if (tid < 432) {                     // (o, c) pairs
        int o = tid / 12, c = tid - o * 12;
        float a = a_s[c], dc = d_s[c];
        const float* src = W2 + o * 972 + c * 81;
        float s = 0.f;
        for (int k = 0; k < 81; ++k) {
            float wv = src[k];
            s += wv;
            W2s[(c * 81 + k) * 36 + o] = wv * a;
        }
        atomicAdd(&b2ws[o], dc * s);
    }
}

// conv2 + relu (BN already folded into W2s/b2ws)
__global__ __launch_bounds__(832) void k_conv2(
    const float* __restrict__ h1, const float* __restrict__ W2s,
    const float* __restrict__ b2ws, float* __restrict__ out)
{
    __shared__ float st[4 * 484];       // 4 d-planes of 22x22

    const int tid = threadIdx.x;
    const int dp = blockIdx.x;          // 0..9  -> d0 = 2*dp
    const int t  = blockIdx.y;          // 0..15
    const int b  = blockIdx.z;          // 0..7
    const int d0 = dp * 2;

    const bool active = tid < 800;      // 2*20*20 positions
    int dd = 0, h = 0, w = 0;
    if (active) { dd = tid / 400; int r = tid - dd * 400; h = r / 20; w = r - h * 20; }

    float acc[36];
#pragma unroll
    for (int o = 0; o < 36; ++o) acc[o] = 0.f;

    const int lbase = dd * 484 + h * 22 + w;

    for (int cm = 0; cm < 12; ++cm) {
        for (int kt = 0; kt < 3; ++kt) {
            __syncthreads();
            // h1[b, cm, t+kt, d0..d0+3, :, :] contiguous: linear copy
            const float* src = h1 + (long)b * S1B + (long)cm * S1C
                             + (long)(t + kt) * S1T + (long)d0 * S1D;
            for (int s = tid; s < 1936; s += 832) st[s] = src[s];
            __syncthreads();
            if (active) {
                const float* wp = W2s + (cm * 81 + kt * 27) * 36;
#pragma unroll
                for (int kd = 0; kd < 3; ++kd)
#pragma unroll
                for (int kh = 0; kh < 3; ++kh)
#pragma unroll
                for (int kw = 0; kw < 3; ++kw) {
                    float xv = st[lbase + kd * 484 + kh * 22 + kw];
                    const float* wq = wp + (kd * 9 + kh * 3 + kw) * 36;
#pragma unroll
                    for (int o = 0; o < 36; ++o) acc[o] = fmaf(wq[o], xv, acc[o]);
                }
            }
        }
    }

    if (active) {
        const long obase = (long)b * S2B + (long)t * S2T + (long)(d0 + dd) * S2D
                         + (long)h * S2H + w;
#pragma unroll
        for (int o = 0; o < 36; ++o)
            out[obase + (long)o * S2O] = fmaxf(acc[o] + b2ws[o], 0.f);
    }
}

extern "C" void kernel_launch(void* const* d_in, const int* in_sizes, int n_in,
                              void* d_out, int out_size, void* d_ws, size_t ws_size,
                              hipStream_t stream) {
    const float* x     = (const float*)d_in[0];
    const float* W1    = (const float*)d_in[1];
    const float* b1    = (const float*)d_in[2];
    const float* gamma = (const float*)d_in[3];
    const float* beta  = (const float*)d_in[4];
    const float* W2    = (const float*)d_in[5];
    const float* b2    = (const float*)d_in[6];
    float* out = (float*)d_out;

    float* ws    = (float*)d_ws;
    float* stats = ws;            // 24 floats
    float* b2ws  = ws + 32;       // 36 floats
    float* W1t   = ws + 128;      // 3888 floats
    float* W2s   = ws + 4096;     // 34992 floats
    float* h1    = ws + 40960;    // 18,399,744 floats (~70 MiB used total)

    hipMemsetAsync(stats, 0, 24 * sizeof(float), stream);
    k_w1t<<<16, 256, 0, stream>>>(W1, W1t);
    k_conv1<<<dim3(11, 18, 8), 1024, 0, stream>>>(x, W1t, b1, h1, stats);
    k_fin<<<1, 512, 0, stream>>>(stats, gamma, beta, W2, b2, W2s, b2ws);
    k_conv2<<<dim3(10, 16, 8), 832, 0, stream>>>(h1, W2s, b2ws, out);
}

// Round 3
// 691.200 us; speedup vs baseline: 2.7307x; 2.7307x over previous
//
#include <hip/hip_runtime.h>

#define EPS 0.001f

typedef __attribute__((ext_vector_type(8))) short bf16x8;
typedef __attribute__((ext_vector_type(4))) float f32x4;

// ---- problem sizes ----
constexpr int Bn = 8, Tx = 20, Dx = 24, Hx = 24, Wx = 24;
constexpr int Cmid = 12, CoutN = 36;
constexpr int T1 = 18, D1 = 22;
constexpr int T2 = 16, D2 = 20;

// x strides (fp32)
constexpr int SXD = 576, SXT = 13824, SXC = 276480;
constexpr long SXB = 1105920;

// h1t: [b][t18][d22][h22][w22][c16] bf16
constexpr int HTW = 16;
constexpr int HTH = 22 * 16;          // 352
constexpr int HTD = 22 * 22 * 16;     // 7744
constexpr int HTT = 22 * HTD;         // 170368
constexpr long HTB = (long)T1 * HTT;  // 3066624

// out strides (fp32)
constexpr int S2D = 400, S2T = 8000, S2O = 128000;
constexpr long S2B = 4608000;

constexpr int NBLK1 = 8 * 18 * 11;    // 1584 conv1 blocks

__device__ __forceinline__ unsigned short f2bf(float f) {
    unsigned u = __builtin_bit_cast(unsigned, f);
    u = (u + 0x7fffu + ((u >> 16) & 1u)) >> 16;
    return (unsigned short)u;
}

// Transpose W1 [o][cin][kt][kd][kh][kw] -> W1t [cin*81 + tap][o] (o contiguous)
__global__ void k_w1t(const float* __restrict__ W1, float* __restrict__ W1t) {
    int i = blockIdx.x * 256 + threadIdx.x;
    if (i < Cmid * 4 * 81) {
        int o = i / 324;
        int r = i - o * 324;
        W1t[r * Cmid + o] = W1[i];
    }
}

// conv1 + relu; writes h1t (bf16 channel-last, c padded to 16) and
// deterministic per-block stats partials part[bid*24 + {c:sum, 12+c:sumsq}]
__global__ __launch_bounds__(1024) void k_conv1(
    const float* __restrict__ x, const float* __restrict__ W1t,
    const float* __restrict__ b1, unsigned short* __restrict__ h1t,
    float* __restrict__ part)
{
    __shared__ float st[4 * 576];
    __shared__ float ssum[16][12], ssq[16][12];

    const int tid = threadIdx.x;
    const int dp = blockIdx.x;          // 0..10 -> d0 = 2*dp
    const int t  = blockIdx.y;          // 0..17
    const int b  = blockIdx.z;          // 0..7
    const int d0 = dp * 2;
    const int bid = (b * 18 + t) * 11 + dp;

    const bool active = tid < 968;
    int dd = 0, h = 0, w = 0;
    if (active) { dd = tid / 484; int r = tid - dd * 484; h = r / 22; w = r - h * 22; }

    float acc[12];
#pragma unroll
    for (int c = 0; c < 12; ++c) acc[c] = 0.f;

    const int lbase = dd * 576 + h * 24 + w;

    for (int cin = 0; cin < 4; ++cin) {
        for (int kt = 0; kt < 3; ++kt) {
            __syncthreads();
            const float* src = x + (long)b * SXB + (long)cin * SXC
                             + (long)(t + kt) * SXT + (long)d0 * SXD;
            for (int s = tid; s < 2304; s += 1024) st[s] = src[s];
            __syncthreads();
            if (active) {
                const float* wp = W1t + (cin * 81 + kt * 27) * 12;
#pragma unroll
                for (int kd = 0; kd < 3; ++kd)
#pragma unroll
                for (int kh = 0; kh < 3; ++kh)
#pragma unroll
                for (int kw = 0; kw < 3; ++kw) {
                    float xv = st[lbase + kd * 576 + kh * 24 + kw];
                    const float* wq = wp + (kd * 9 + kh * 3 + kw) * 12;
#pragma unroll
                    for (int c = 0; c < 12; ++c) acc[c] = fmaf(wq[c], xv, acc[c]);
                }
            }
        }
    }

    float v[12];
#pragma unroll
    for (int c = 0; c < 12; ++c)
        v[c] = active ? fmaxf(acc[c] + b1[c], 0.f) : 0.f;

    const int lane = tid & 63;
    const int wv   = tid >> 6;
#pragma unroll
    for (int c = 0; c < 12; ++c) {
        float s = v[c], q = v[c] * v[c];
#pragma unroll
        for (int off = 32; off > 0; off >>= 1) {
            s += __shfl_down(s, off);
            q += __shfl_down(q, off);
        }
        if (lane == 0) { ssum[wv][c] = s; ssq[wv][c] = q; }
    }

    if (active) {
        const long tb = (long)b * HTB + (long)t * HTT + (long)(d0 + dd) * HTD
                      + (long)h * HTH + (long)w * HTW;
        uint4 p0, p1;
        p0.x = (unsigned)f2bf(v[0]) | ((unsigned)f2bf(v[1]) << 16);
        p0.y = (unsigned)f2bf(v[2]) | ((unsigned)f2bf(v[3]) << 16);
        p0.z = (unsigned)f2bf(v[4]) | ((unsigned)f2bf(v[5]) << 16);
        p0.w = (unsigned)f2bf(v[6]) | ((unsigned)f2bf(v[7]) << 16);
        p1.x = (unsigned)f2bf(v[8]) | ((unsigned)f2bf(v[9]) << 16);
        p1.y = (unsigned)f2bf(v[10]) | ((unsigned)f2bf(v[11]) << 16);
        p1.z = 0u; p1.w = 0u;
        *(uint4*)(h1t + tb) = p0;
        *(uint4*)(h1t + tb + 8) = p1;
    }

    __syncthreads();
    // deterministic in-block reduction of 16 wave partials
    if (tid < 12) {
        float s = 0.f;
#pragma unroll
        for (int i = 0; i < 16; ++i) s += ssum[i][tid];
        part[bid * 24 + tid] = s;
    } else if (tid < 24) {
        float s = 0.f;
#pragma unroll
        for (int i = 0; i < 16; ++i) s += ssq[i][tid - 12];
        part[bid * 24 + tid] = s;
    }
}

// deterministic cross-block reduction: 24 blocks, one per stat channel
__global__ void k_red(const float* __restrict__ part, float* __restrict__ stats2) {
    __shared__ float s[256];
    const int c = blockIdx.x;      // 0..23
    const int tid = threadIdx.x;   // 0..255
    float acc = 0.f;
    for (int i = tid; i < NBLK1; i += 256) acc += part[i * 24 + c];
    s[tid] = acc;
    __syncthreads();
    for (int off = 128; off > 0; off >>= 1) {
        if (tid < off) s[tid] += s[tid + off];
        __syncthreads();
    }
    if (tid == 0) stats2[c] = s[0];
}

// finalize BN: a[c]; b2ws[o] = b2[o] + sum_c d_c * sum_taps W2[o][c][tap]
__global__ void k_fin1(const float* __restrict__ stats2, const float* __restrict__ gamma,
                       const float* __restrict__ beta, const float* __restrict__ W2,
                       const float* __restrict__ b2, float* __restrict__ abuf,
                       float* __restrict__ b2ws)
{
    __shared__ float a_s[12], d_s[12];
    const int tid = threadIdx.x;  // 64
    if (tid < 12) {
        const float N = 1533312.f;   // 8*18*22*22*22
        float mean = stats2[tid] / N;
        float var  = stats2[12 + tid] / N - mean * mean;
        float a = gamma[tid] * rsqrtf(var + EPS);
        abuf[tid] = a_s[tid] = a;
        d_s[tid] = beta[tid] - mean * a;
    }
    __syncthreads();
    if (tid < 36) {
        float s = b2[tid];
        for (int c = 0; c < 12; ++c) {
            const float* p = W2 + tid * 972 + c * 81;
            float tsum = 0.f;
            for (int k = 0; k < 81; ++k) tsum += p[k];
            s += d_s[c] * tsum;
        }
        b2ws[tid] = s;
    }
}

// Build A-operand fragment-ordered weights Wf.
// Block bi = ((g*3 + mt)*2 + ch); g = kt*9 + kd*3 + kh.
// A[m=lane&15 -> o_local][k = (lane>>4)*8 + j], k' = ch*32 + k; kw=k'/16, c=k'%16; k'>=48 -> 0.
__global__ void k_fin2(const float* __restrict__ W2, const float* __restrict__ abuf,
                       unsigned short* __restrict__ Wf)
{
    const int bi = blockIdx.x;       // 0..161
    const int lane = threadIdx.x;    // 0..63
    const int ch = bi & 1;
    const int tmp = bi >> 1;
    const int mt = tmp % 3;
    const int g = tmp / 3;
    const int kt = g / 9, g9 = g % 9, kd = g9 / 3, kh = g9 % 3;
    const int o = mt * 16 + (lane & 15);

    unsigned short vals[8];
#pragma unroll
    for (int j = 0; j < 8; ++j) {
        int k = ch * 32 + ((lane >> 4) << 3) + j;
        float v = 0.f;
        if (k < 48 && o < 36) {
            int kw = k >> 4, c = k & 15;
            if (c < 12)
                v = W2[o * 972 + c * 81 + kt * 27 + kd * 9 + kh * 3 + kw] * abuf[c];
        }
        vals[j] = f2bf(v);
    }
    uint4 pk;
    pk.x = (unsigned)vals[0] | ((unsigned)vals[1] << 16);
    pk.y = (unsigned)vals[2] | ((unsigned)vals[3] << 16);
    pk.z = (unsigned)vals[4] | ((unsigned)vals[5] << 16);
    pk.w = (unsigned)vals[6] | ((unsigned)vals[7] << 16);
    *(uint4*)(Wf + bi * 512 + lane * 8) = pk;
}

// MFMA implicit-GEMM conv2. Block = (d, t, b) output plane (20x20 = 25 pos-tiles).
// LDS: 3 input d-planes, layout per plane: 16B unit index = h*44 + chalf*22 + w.
__global__ __launch_bounds__(320, 3) void k_conv2m(
    const unsigned short* __restrict__ h1t, const unsigned short* __restrict__ Wf,
    const float* __restrict__ b2ws, float* __restrict__ out)
{
    __shared__ char lds[3 * 15488];

    const int tid  = threadIdx.x;
    const int lane = tid & 63;
    const int wv   = tid >> 6;     // 0..4
    const int d = blockIdx.x;      // 0..19
    const int t = blockIdx.y;      // 0..15
    const int b = blockIdx.z;      // 0..7

    const int n16 = lane & 15;
    const int q   = lane >> 4;

    int posbase[5], pb[5];
#pragma unroll
    for (int u = 0; u < 5; ++u) {
        int p = (wv * 5 + u) * 16 + n16;
        int h = p / 20, w = p - h * 20;
        pb[u] = p;
        posbase[u] = h * 704 + w * 16;
    }
    const int qoff0 = (q & 1) * 352 + (q >> 1) * 16;
    const int qoff1 = (q & 1) * 352 + 32;

    f32x4 acc[5][3];
#pragma unroll
    for (int u = 0; u < 5; ++u)
#pragma unroll
        for (int mt = 0; mt < 3; ++mt)
            acc[u][mt] = (f32x4){0.f, 0.f, 0.f, 0.f};

    for (int kt = 0; kt < 3; ++kt) {
        __syncthreads();
        {
            const unsigned short* src = h1t + (long)b * HTB + (long)(t + kt) * HTT
                                      + (long)d * HTD;
            for (int i = tid; i < 2904; i += 320) {
                int pl = i / 968; int r = i - pl * 968;
                int h = r / 44; int r2 = r - h * 44;
                int w = r2 >> 1, chh = r2 & 1;
                int dst = pl * 968 + h * 44 + chh * 22 + w;
                *(uint4*)(lds + dst * 16) = *(const uint4*)(src + i * 8);
            }
        }
        __syncthreads();

        for (int g9 = 0; g9 < 9; ++g9) {
            const int kd = g9 / 3, kh = g9 - kd * 3;
            const int g = kt * 9 + g9;

            bf16x8 A[3][2];
#pragma unroll
            for (int mt = 0; mt < 3; ++mt)
#pragma unroll
                for (int c2 = 0; c2 < 2; ++c2)
                    A[mt][c2] = *(const bf16x8*)(Wf + (((g * 3 + mt) * 2 + c2) << 9) + lane * 8);

            const int goff = kd * 15488 + kh * 704;
#pragma unroll
            for (int u = 0; u < 5; ++u) {
                bf16x8 b0 = *(const bf16x8*)(lds + posbase[u] + goff + qoff0);
                bf16x8 b1 = *(const bf16x8*)(lds + posbase[u] + goff + qoff1);
#pragma unroll
                for (int mt = 0; mt < 3; ++mt) {
                    acc[u][mt] = __builtin_amdgcn_mfma_f32_16x16x32_bf16(A[mt][0], b0, acc[u][mt], 0, 0, 0);
                    acc[u][mt] = __builtin_amdgcn_mfma_f32_16x16x32_bf16(A[mt][1], b1, acc[u][mt], 0, 0, 0);
                }
            }
        }
    }

    // epilogue: D col = lane&15 = position, row = q*4 + r = o_local
    const long ob = (long)b * S2B + (long)t * S2T + (long)d * S2D;
#pragma unroll
    for (int mt = 0; mt < 3; ++mt)
#pragma unroll
    for (int r = 0; r < 4; ++r) {
        const int o = mt * 16 + q * 4 + r;
        if (o < 36) {
            const float bias = b2ws[o];
#pragma unroll
            for (int u = 0; u < 5; ++u)
                out[ob + (long)o * S2O + pb[u]] = fmaxf(acc[u][mt][r] + bias, 0.f);
        }
    }
}

extern "C" void kernel_launch(void* const* d_in, const int* in_sizes, int n_in,
                              void* d_out, int out_size, void* d_ws, size_t ws_size,
                              hipStream_t stream) {
    const float* x     = (const float*)d_in[0];
    const float* W1    = (const float*)d_in[1];
    const float* b1    = (const float*)d_in[2];
    const float* gamma = (const float*)d_in[3];
    const float* beta  = (const float*)d_in[4];
    const float* W2    = (const float*)d_in[5];
    const float* b2    = (const float*)d_in[6];
    float* out = (float*)d_out;

    float* ws     = (float*)d_ws;
    float* stats2 = ws;                                  // 24 f
    float* abuf   = ws + 32;                             // 12 f
    float* b2ws   = ws + 64;                             // 36 f
    float* W1t    = ws + 128;                            // 3888 f (bytes 512..16064)
    unsigned short* Wf  = (unsigned short*)((char*)d_ws + 16384);   // 165,888 B
    float* part   = (float*)((char*)d_ws + 196608);      // 38,016 f (ends ~348 KB)
    unsigned short* h1t = (unsigned short*)((char*)d_ws + 393216);  // ~49 MB

    k_w1t<<<16, 256, 0, stream>>>(W1, W1t);
    k_conv1<<<dim3(11, 18, 8), 1024, 0, stream>>>(x, W1t, b1, h1t, part);
    k_red<<<24, 256, 0, stream>>>(part, stats2);
    k_fin1<<<1, 64, 0, stream>>>(stats2, gamma, beta, W2, b2, abuf, b2ws);
    k_fin2<<<162, 64, 0, stream>>>(W2, abuf, Wf);
    k_conv2m<<<dim3(20, 16, 8), 320, 0, stream>>>(h1t, Wf, b2ws, out);
}

// Round 4
// 512.823 us; speedup vs baseline: 3.6805x; 1.3478x over previous
//
#include <hip/hip_runtime.h>

#define EPS 0.001f

typedef __attribute__((ext_vector_type(8))) short bf16x8;
typedef __attribute__((ext_vector_type(4))) short bf16x4;
typedef __attribute__((ext_vector_type(4))) float f32x4;

// ---- problem sizes ----
constexpr int Bn = 8, Tx = 20, Dx = 24, Hx = 24, Wx = 24;
constexpr int Cmid = 12, CoutN = 36;
constexpr int T1 = 18, D1 = 22;
constexpr int T2 = 16, D2 = 20;

// x strides (fp32)
constexpr int SXD = 576, SXT = 13824, SXC = 276480;
constexpr long SXB = 1105920;

// xt: [b][t20][d24][h24][w24][c4] bf16
constexpr int XTD = 2304, XTT = 55296;
constexpr long XTB = (long)Tx * XTT;     // 1105920

// h1t: [b][t18][d22][h22][w22][c16] bf16
constexpr int HTW = 16;
constexpr int HTH = 22 * 16;          // 352
constexpr int HTD = 22 * 22 * 16;     // 7744
constexpr int HTT = 22 * HTD;         // 170368
constexpr long HTB = (long)T1 * HTT;  // 3066624

// out strides (fp32)
constexpr int S2D = 400, S2T = 8000, S2O = 128000;
constexpr long S2B = 4608000;

constexpr int NBLK1 = 8 * 18 * 22;    // 3168 conv1m blocks

__device__ __forceinline__ unsigned short f2bf(float f) {
    unsigned u = __builtin_bit_cast(unsigned, f);
    u = (u + 0x7fffu + ((u >> 16) & 1u)) >> 16;
    return (unsigned short)u;
}

// x [b][cin][t][d][h][w] fp32 -> xt [b][t][d][h][w][c4] bf16
__global__ __launch_bounds__(576) void k_xt(const float* __restrict__ x,
                                            unsigned short* __restrict__ xt) {
    const int tid = threadIdx.x;          // 0..575 = h*24+w
    const int d = blockIdx.x, t = blockIdx.y, b = blockIdx.z;
    const float* src = x + (long)b * SXB + (long)t * SXT + (long)d * SXD + tid;
    float v0 = src[0];
    float v1 = src[SXC];
    float v2 = src[2 * SXC];
    float v3 = src[3 * SXC];
    uint2 p;
    p.x = (unsigned)f2bf(v0) | ((unsigned)f2bf(v1) << 16);
    p.y = (unsigned)f2bf(v2) | ((unsigned)f2bf(v3) << 16);
    *(uint2*)(xt + (long)b * XTB + (long)t * XTT + (long)d * XTD + tid * 4) = p;
}

// Build conv1 A-fragments Wf1[p=0..13][lane][8]
// chunk p pairs groups g=2p, 2p+1 (g=kt*9+kd*3+kh; g==27 -> zero).
// k = q*8+j; gsel=k>>4; r=k&15; kw=r>>2; cin=r&3; m=lane&15 -> cout.
__global__ void k_finW1(const float* __restrict__ W1, unsigned short* __restrict__ Wf1) {
    const int p = blockIdx.x;        // 0..13
    const int lane = threadIdx.x;    // 0..63
    const int m = lane & 15;
    const int q = lane >> 4;
    unsigned short vals[8];
#pragma unroll
    for (int j = 0; j < 8; ++j) {
        int kk = q * 8 + j;
        int g = 2 * p + (kk >> 4);
        int r = kk & 15;
        int kw = r >> 2, cin = r & 3;
        float v = 0.f;
        if (m < 12 && kw < 3 && g < 27) {
            int kt = g / 9, g9 = g - kt * 9, kd = g9 / 3, kh = g9 - kd * 3;
            v = W1[m * 324 + cin * 81 + kt * 27 + kd * 9 + kh * 3 + kw];
        }
        vals[j] = f2bf(v);
    }
    uint4 pk;
    pk.x = (unsigned)vals[0] | ((unsigned)vals[1] << 16);
    pk.y = (unsigned)vals[2] | ((unsigned)vals[3] << 16);
    pk.z = (unsigned)vals[4] | ((unsigned)vals[5] << 16);
    pk.w = (unsigned)vals[6] | ((unsigned)vals[7] << 16);
    *(uint4*)(Wf1 + p * 512 + lane * 8) = pk;
}

// MFMA implicit-GEMM conv1. Block = (d,t,b) output plane 22x22 = 484 pos.
// LDS: 9 planes (kt,kd) of xt [24h][24w][4c] bf16 = 4608 B each.
__global__ __launch_bounds__(512, 4) void k_conv1m(
    const unsigned short* __restrict__ xt, const unsigned short* __restrict__ Wf1,
    const float* __restrict__ b1, unsigned short* __restrict__ h1t,
    float* __restrict__ part)
{
    __shared__ char lds[9 * 4608 + 16];
    __shared__ float ssum[8][12], ssq[8][12];

    const int tid  = threadIdx.x;
    const int lane = tid & 63;
    const int wv   = tid >> 6;     // 0..7
    const int d = blockIdx.x;      // 0..21
    const int t = blockIdx.y;      // 0..17
    const int b = blockIdx.z;      // 0..7
    const int bid = (b * 18 + t) * 22 + d;

    const int n16 = lane & 15;
    const int q   = lane >> 4;

    // stage 9 planes: p = kt*3+kd
    {
        for (int i = tid; i < 2592; i += 512) {
            int p = i / 288, r = i - p * 288;
            int kt = p / 3, kd = p - kt * 3;
            const unsigned short* src = xt + (long)b * XTB + (long)(t + kt) * XTT
                                      + (long)(d + kd) * XTD + r * 8;
            *(uint4*)(lds + i * 16) = *(const uint4*)src;
        }
    }

    // A fragments (global, L2-resident)
    bf16x8 A[14];
#pragma unroll
    for (int p = 0; p < 14; ++p)
        A[p] = *(const bf16x8*)(Wf1 + p * 512 + lane * 8);

    // per-tile position info
    int hh[4], ww[4], nn[4];
#pragma unroll
    for (int u = 0; u < 4; ++u) {
        int n = (wv * 4 + u) * 16 + n16;
        nn[u] = n;
        int nc = n < 484 ? n : 483;
        hh[u] = nc / 22;
        ww[u] = nc - hh[u] * 22;
    }

    f32x4 acc[4];
#pragma unroll
    for (int u = 0; u < 4; ++u) acc[u] = (f32x4){0.f, 0.f, 0.f, 0.f};

    __syncthreads();

#pragma unroll
    for (int p = 0; p < 14; ++p) {
        int gq = 2 * p + (q >> 1);
        int gc = gq < 27 ? gq : 26;
        int kt = gc / 9, g9 = gc - kt * 9, kd = g9 / 3, kh = g9 - kd * 3;
        const int off = (kt * 3 + kd) * 4608 + kh * 192 + (q & 1) * 16;
#pragma unroll
        for (int u = 0; u < 4; ++u) {
            const int addr = off + hh[u] * 192 + ww[u] * 8;
            bf16x4 lo = *(const bf16x4*)(lds + addr);
            bf16x4 hi = *(const bf16x4*)(lds + addr + 8);
            bf16x8 bb;
            bb[0] = lo[0]; bb[1] = lo[1]; bb[2] = lo[2]; bb[3] = lo[3];
            bb[4] = hi[0]; bb[5] = hi[1]; bb[6] = hi[2]; bb[7] = hi[3];
            acc[u] = __builtin_amdgcn_mfma_f32_16x16x32_bf16(A[p], bb, acc[u], 0, 0, 0);
        }
    }

    // epilogue: D row = q*4+r = cout, col = n16 = position
    const int c0 = q * 4;
    float bias[4];
#pragma unroll
    for (int r = 0; r < 4; ++r) bias[r] = (c0 + r) < 12 ? b1[c0 + r] : 0.f;

    float ls[4] = {0.f, 0.f, 0.f, 0.f}, lq[4] = {0.f, 0.f, 0.f, 0.f};
#pragma unroll
    for (int u = 0; u < 4; ++u) {
        const bool valid = nn[u] < 484;
        float v[4];
#pragma unroll
        for (int r = 0; r < 4; ++r) {
            float val = fmaxf(acc[u][r] + bias[r], 0.f);
            v[r] = val;
            if (valid) { ls[r] += val; lq[r] += val * val; }
        }
        if (valid) {
            const long ob = (long)b * HTB + (long)t * HTT + (long)d * HTD
                          + (long)hh[u] * HTH + (long)ww[u] * HTW + c0;
            uint2 pk;
            pk.x = (unsigned)f2bf(v[0]) | ((unsigned)f2bf(v[1]) << 16);
            pk.y = (unsigned)f2bf(v[2]) | ((unsigned)f2bf(v[3]) << 16);
            *(uint2*)(h1t + ob) = pk;
        }
    }

    // stats: reduce over n16 within q-group
#pragma unroll
    for (int off = 8; off > 0; off >>= 1) {
#pragma unroll
        for (int r = 0; r < 4; ++r) {
            ls[r] += __shfl_xor(ls[r], off);
            lq[r] += __shfl_xor(lq[r], off);
        }
    }
    if (n16 == 0 && q < 3) {
#pragma unroll
        for (int r = 0; r < 4; ++r) {
            ssum[wv][c0 + r] = ls[r];
            ssq[wv][c0 + r] = lq[r];
        }
    }
    __syncthreads();
    if (tid < 12) {
        float s = 0.f;
#pragma unroll
        for (int i = 0; i < 8; ++i) s += ssum[i][tid];
        part[bid * 24 + tid] = s;
    } else if (tid < 24) {
        float s = 0.f;
#pragma unroll
        for (int i = 0; i < 8; ++i) s += ssq[i][tid - 12];
        part[bid * 24 + tid] = s;
    }
}

// deterministic cross-block reduction: 24 blocks, one per stat channel
__global__ void k_red(const float* __restrict__ part, float* __restrict__ stats2) {
    __shared__ float s[256];
    const int c = blockIdx.x;
    const int tid = threadIdx.x;
    float acc = 0.f;
    for (int i = tid; i < NBLK1; i += 256) acc += part[i * 24 + c];
    s[tid] = acc;
    __syncthreads();
    for (int off = 128; off > 0; off >>= 1) {
        if (tid < off) s[tid] += s[tid + off];
        __syncthreads();
    }
    if (tid == 0) stats2[c] = s[0];
}

// finalize BN: a[c]; b2ws[o] = b2[o] + sum_c d_c * sum_taps W2[o][c][tap]
__global__ void k_fin1(const float* __restrict__ stats2, const float* __restrict__ gamma,
                       const float* __restrict__ beta, const float* __restrict__ W2,
                       const float* __restrict__ b2, float* __restrict__ abuf,
                       float* __restrict__ b2ws)
{
    __shared__ float a_s[12], d_s[12];
    const int tid = threadIdx.x;  // 64
    if (tid < 12) {
        const float N = 1533312.f;   // 8*18*22*22*22
        float mean = stats2[tid] / N;
        float var  = stats2[12 + tid] / N - mean * mean;
        float a = gamma[tid] * rsqrtf(var + EPS);
        abuf[tid] = a_s[tid] = a;
        d_s[tid] = beta[tid] - mean * a;
    }
    __syncthreads();
    if (tid < 36) {
        float s = b2[tid];
        for (int c = 0; c < 12; ++c) {
            const float* p = W2 + tid * 972 + c * 81;
            float tsum = 0.f;
            for (int k = 0; k < 81; ++k) tsum += p[k];
            s += d_s[c] * tsum;
        }
        b2ws[tid] = s;
    }
}

// Build conv2 A-operand fragment-ordered weights Wf (BN-scaled).
__global__ void k_fin2(const float* __restrict__ W2, const float* __restrict__ abuf,
                       unsigned short* __restrict__ Wf)
{
    const int bi = blockIdx.x;       // 0..161
    const int lane = threadIdx.x;    // 0..63
    const int ch = bi & 1;
    const int tmp = bi >> 1;
    const int mt = tmp % 3;
    const int g = tmp / 3;
    const int kt = g / 9, g9 = g % 9, kd = g9 / 3, kh = g9 % 3;
    const int o = mt * 16 + (lane & 15);

    unsigned short vals[8];
#pragma unroll
    for (int j = 0; j < 8; ++j) {
        int k = ch * 32 + ((lane >> 4) << 3) + j;
        float v = 0.f;
        if (k < 48 && o < 36) {
            int kw = k >> 4, c = k & 15;
            if (c < 12)
                v = W2[o * 972 + c * 81 + kt * 27 + kd * 9 + kh * 3 + kw] * abuf[c];
        }
        vals[j] = f2bf(v);
    }
    uint4 pk;
    pk.x = (unsigned)vals[0] | ((unsigned)vals[1] << 16);
    pk.y = (unsigned)vals[2] | ((unsigned)vals[3] << 16);
    pk.z = (unsigned)vals[4] | ((unsigned)vals[5] << 16);
    pk.w = (unsigned)vals[6] | ((unsigned)vals[7] << 16);
    *(uint4*)(Wf + bi * 512 + lane * 8) = pk;
}

// MFMA implicit-GEMM conv2. Block = (d, t, b) output plane (20x20 = 25 pos-tiles).
__global__ __launch_bounds__(320, 3) void k_conv2m(
    const unsigned short* __restrict__ h1t, const unsigned short* __restrict__ Wf,
    const float* __restrict__ b2ws, float* __restrict__ out)
{
    __shared__ char lds[3 * 15488];

    const int tid  = threadIdx.x;
    const int lane = tid & 63;
    const int wv   = tid >> 6;     // 0..4
    const int d = blockIdx.x;      // 0..19
    const int t = blockIdx.y;      // 0..15
    const int b = blockIdx.z;      // 0..7

    const int n16 = lane & 15;
    const int q   = lane >> 4;

    int posbase[5], pb[5];
#pragma unroll
    for (int u = 0; u < 5; ++u) {
        int p = (wv * 5 + u) * 16 + n16;
        int h = p / 20, w = p - h * 20;
        pb[u] = p;
        posbase[u] = h * 704 + w * 16;
    }
    const int qoff0 = (q & 1) * 352 + (q >> 1) * 16;
    const int qoff1 = (q & 1) * 352 + 32;

    f32x4 acc[5][3];
#pragma unroll
    for (int u = 0; u < 5; ++u)
#pragma unroll
        for (int mt = 0; mt < 3; ++mt)
            acc[u][mt] = (f32x4){0.f, 0.f, 0.f, 0.f};

    for (int kt = 0; kt < 3; ++kt) {
        __syncthreads();
        {
            const unsigned short* src = h1t + (long)b * HTB + (long)(t + kt) * HTT
                                      + (long)d * HTD;
            for (int i = tid; i < 2904; i += 320) {
                int pl = i / 968; int r = i - pl * 968;
                int h = r / 44; int r2 = r - h * 44;
                int w = r2 >> 1, chh = r2 & 1;
                int dst = pl * 968 + h * 44 + chh * 22 + w;
                *(uint4*)(lds + dst * 16) = *(const uint4*)(src + i * 8);
            }
        }
        __syncthreads();

        for (int g9 = 0; g9 < 9; ++g9) {
            const int kd = g9 / 3, kh = g9 - kd * 3;
            const int g = kt * 9 + g9;

            bf16x8 A[3][2];
#pragma unroll
            for (int mt = 0; mt < 3; ++mt)
#pragma unroll
                for (int c2 = 0; c2 < 2; ++c2)
                    A[mt][c2] = *(const bf16x8*)(Wf + (((g * 3 + mt) * 2 + c2) << 9) + lane * 8);

            const int goff = kd * 15488 + kh * 704;
#pragma unroll
            for (int u = 0; u < 5; ++u) {
                bf16x8 b0 = *(const bf16x8*)(lds + posbase[u] + goff + qoff0);
                bf16x8 b1 = *(const bf16x8*)(lds + posbase[u] + goff + qoff1);
#pragma unroll
                for (int mt = 0; mt < 3; ++mt) {
                    acc[u][mt] = __builtin_amdgcn_mfma_f32_16x16x32_bf16(A[mt][0], b0, acc[u][mt], 0, 0, 0);
                    acc[u][mt] = __builtin_amdgcn_mfma_f32_16x16x32_bf16(A[mt][1], b1, acc[u][mt], 0, 0, 0);
                }
            }
        }
    }

    const long ob = (long)b * S2B + (long)t * S2T + (long)d * S2D;
#pragma unroll
    for (int mt = 0; mt < 3; ++mt)
#pragma unroll
    for (int r = 0; r < 4; ++r) {
        const int o = mt * 16 + q * 4 + r;
        if (o < 36) {
            const float bias = b2ws[o];
#pragma unroll
            for (int u = 0; u < 5; ++u)
                out[ob + (long)o * S2O + pb[u]] = fmaxf(acc[u][mt][r] + bias, 0.f);
        }
    }
}

extern "C" void kernel_launch(void* const* d_in, const int* in_sizes, int n_in,
                              void* d_out, int out_size, void* d_ws, size_t ws_size,
                              hipStream_t stream) {
    const float* x     = (const float*)d_in[0];
    const float* W1    = (const float*)d_in[1];
    const float* b1    = (const float*)d_in[2];
    const float* gamma = (const float*)d_in[3];
    const float* beta  = (const float*)d_in[4];
    const float* W2    = (const float*)d_in[5];
    const float* b2    = (const float*)d_in[6];
    float* out = (float*)d_out;

    float* ws     = (float*)d_ws;
    float* stats2 = ws;                                  // 24 f
    float* abuf   = ws + 32;                             // 12 f
    float* b2ws   = ws + 64;                             // 36 f
    unsigned short* Wf1 = (unsigned short*)((char*)d_ws + 1024);    // 14336 B
    unsigned short* Wf  = (unsigned short*)((char*)d_ws + 16384);   // 165888 B
    float* part   = (float*)((char*)d_ws + 196608);      // 3168*24 f = 304128 B
    unsigned short* h1t = (unsigned short*)((char*)d_ws + 524288);  // 49.07 MB
    unsigned short* xt  = (unsigned short*)((char*)d_ws + 50331648); // 17.7 MB

    k_xt<<<dim3(24, 20, 8), 576, 0, stream>>>(x, xt);
    k_finW1<<<14, 64, 0, stream>>>(W1, Wf1);
    k_conv1m<<<dim3(22, 18, 8), 512, 0, stream>>>(xt, Wf1, b1, h1t, part);
    k_red<<<24, 256, 0, stream>>>(part, stats2);
    k_fin1<<<1, 64, 0, stream>>>(stats2, gamma, beta, W2, b2, abuf, b2ws);
    k_fin2<<<162, 64, 0, stream>>>(W2, abuf, Wf);
    k_conv2m<<<dim3(20, 16, 8), 320, 0, stream>>>(h1t, Wf, b2ws, out);
}